// Round 8
// baseline (157.913 us; speedup 1.0000x reference)
//
#include <hip/hip_runtime.h>
#include <cfloat>

// VQ-VAE nearest-codebook via bf16x3 split MFMA, v4:
//   proven R5 structure, occupancy 2 blocks/CU (4 waves/SIMD):
//   - 512-thr block = 8 waves = 8 code-tiles; 64 rows/block (2 accs/wave)
//   - single 64KB LDS buffer (stage -> sync -> compute -> sync)
//   - pre-split codebook (hi/lo bf16) in ws, staged via global_load_lds
// d_out (f32): [0,NQ) quantized | [NQ] vq_loss | [NQ+1] commitment | [NQ+2,+N) idx
// d_ws  (f32): [0,K) r2 | [K] loss | [8448...) split codebook (2 MB)

typedef __bf16 bf16x8 __attribute__((ext_vector_type(8)));
typedef float  f32x16 __attribute__((ext_vector_type(16)));

constexpr int N_ROWS = 32768;
constexpr int K_CB   = 8192;
constexpr int D_DIM  = 64;
constexpr size_t NQ  = (size_t)N_ROWS * D_DIM;
constexpr int WS_LOSS = K_CB;
constexpr size_t WS_SPLIT_F   = 8448;
constexpr size_t SPLIT_BYTES  = (size_t)K_CB * D_DIM * 4;   // 2 MB
constexpr size_t WS_NEED      = WS_SPLIT_F * 4 + SPLIT_BYTES;
constexpr int NROUND = K_CB / 256;                          // 32 rounds of 256 codes

#define GLL16(gp, lp)                                                          \
  __builtin_amdgcn_global_load_lds(                                            \
      (const __attribute__((address_space(1))) unsigned int*)(gp),             \
      (__attribute__((address_space(3))) unsigned int*)(lp), 16, 0, 0)

// ---------------------------------------------------------------- prep: r2
__global__ __launch_bounds__(256) void vq_prep(const float* __restrict__ cb,
                                               float* __restrict__ ws) {
  const int k = blockIdx.x * 256 + threadIdx.x;
  if (k == 0) ws[WS_LOSS] = 0.0f;
  const float4* p = reinterpret_cast<const float4*>(cb) + (size_t)k * 16;
  float s0 = 0.f, s1 = 0.f, s2 = 0.f, s3 = 0.f;
#pragma unroll
  for (int j = 0; j < 16; ++j) {
    float4 v = p[j];
    s0 = fmaf(v.x, v.x, s0); s1 = fmaf(v.y, v.y, s1);
    s2 = fmaf(v.z, v.z, s2); s3 = fmaf(v.w, v.w, s3);
  }
  ws[k] = (s0 + s1) + (s2 + s3);
}

// ------------------------------------------------- prep: split codebook in ws
// Round r (256 codes) -> 64KB block: t(=k>>5&7)*8192 + h*4096 + ch*512 + c*16.
__global__ __launch_bounds__(256) void vq_split(const float* __restrict__ cb,
                                                float* __restrict__ ws) {
  const int u  = blockIdx.x * 256 + threadIdx.x;   // 65536 threads
  const int k  = u >> 3, ch = u & 7;
  const int r  = k >> 8, t = (k >> 5) & 7, c = k & 31;
  const float* src = cb + (size_t)k * D_DIM + ch * 8;
  float4 f0 = *reinterpret_cast<const float4*>(src);
  float4 f1 = *reinterpret_cast<const float4*>(src + 4);
  float xs[8] = {f0.x, f0.y, f0.z, f0.w, f1.x, f1.y, f1.z, f1.w};
  bf16x8 hi, lo;
#pragma unroll
  for (int j = 0; j < 8; ++j) {
    __bf16 h = (__bf16)xs[j];
    hi[j] = h;
    lo[j] = (__bf16)(xs[j] - (float)h);
  }
  char* base = reinterpret_cast<char*>(ws + WS_SPLIT_F) +
               (size_t)r * 65536 + (size_t)t * 8192 + (size_t)ch * 512 + (size_t)c * 16;
  *reinterpret_cast<bf16x8*>(base)        = hi;
  *reinterpret_cast<bf16x8*>(base + 4096) = lo;
}

// ---------------------------------------------------------------- main kernel
// 512 thr = 8 waves; wave w owns code-tile t=w (32 codes) of each round and
// 2 row-accumulators (q=0,1 -> rows rowbase + q*32 + c). 64 rows per block.
__global__ __launch_bounds__(512, 4) void vq_mfma8(const float* __restrict__ z,
                                                   const float* __restrict__ cb,
                                                   float* __restrict__ ws,
                                                   float* __restrict__ out) {
  __shared__ __attribute__((aligned(16))) unsigned char lds[65536];

  const int tid = threadIdx.x;
  const int w = tid >> 6, l = tid & 63;
  const int c = l & 31, g = l >> 5;
  const int rowbase = blockIdx.x * 64;

  // --- z fragments for my 2 rowsets, hi/lo split, registers forever ---
  bf16x8 zh[2][4], zl[2][4];
#pragma unroll
  for (int q = 0; q < 2; ++q) {
    const float* zr = z + (size_t)(rowbase + q * 32 + c) * D_DIM + 8 * g;
#pragma unroll
    for (int s = 0; s < 4; ++s) {
      float4 f0 = *reinterpret_cast<const float4*>(zr + 16 * s);
      float4 f1 = *reinterpret_cast<const float4*>(zr + 16 * s + 4);
      float xs[8] = {f0.x, f0.y, f0.z, f0.w, f1.x, f1.y, f1.z, f1.w};
#pragma unroll
      for (int j = 0; j < 8; ++j) {
        __bf16 h = (__bf16)xs[j];
        zh[q][s][j] = h;
        zl[q][s][j] = (__bf16)(xs[j] - (float)h);
      }
    }
  }

  // staging: per-lane global src; wave-uniform LDS base (proven R5 pattern).
  const char* sg = reinterpret_cast<const char*>(ws + WS_SPLIT_F) +
                   (size_t)w * 1024 + (size_t)l * 16;

  float best0 = FLT_MAX, best1 = FLT_MAX;
  int   bp0 = 0, bp1 = 0;   // (round<<4) | i

  for (int r = 0; r < NROUND; ++r) {
    // stage round r (64KB) into the single buffer
    const char* s2 = sg + (size_t)r * 65536;
#pragma unroll
    for (int j = 0; j < 8; ++j)
      GLL16(s2 + j * 8192, lds + j * 8192 + w * 1024);
    __syncthreads();   // drains vmcnt: stage visible to all waves

    // code fragments for tile w: [t=w][h][ch=2s+g][c]
    const unsigned rb = (unsigned)w * 8192u + (unsigned)g * 512u + (unsigned)c * 16u;
    f32x16 a0, a1;
#pragma unroll
    for (int i = 0; i < 16; ++i) { a0[i] = 0.f; a1[i] = 0.f; }

    __builtin_amdgcn_s_setprio(1);
#pragma unroll
    for (int s = 0; s < 4; ++s) {
      bf16x8 ca = *reinterpret_cast<const bf16x8*>(lds + rb + s * 1024);
      bf16x8 cl = *reinterpret_cast<const bf16x8*>(lds + rb + s * 1024 + 4096);
      a0 = __builtin_amdgcn_mfma_f32_32x32x16_bf16(ca, zh[0][s], a0, 0, 0, 0);
      a1 = __builtin_amdgcn_mfma_f32_32x32x16_bf16(ca, zh[1][s], a1, 0, 0, 0);
      a0 = __builtin_amdgcn_mfma_f32_32x32x16_bf16(ca, zl[0][s], a0, 0, 0, 0);
      a1 = __builtin_amdgcn_mfma_f32_32x32x16_bf16(ca, zl[1][s], a1, 0, 0, 0);
      a0 = __builtin_amdgcn_mfma_f32_32x32x16_bf16(cl, zh[0][s], a0, 0, 0, 0);
      a1 = __builtin_amdgcn_mfma_f32_32x32x16_bf16(cl, zh[1][s], a1, 0, 0, 0);
    }
    __builtin_amdgcn_s_setprio(0);

    // scores: sc = r2[k] - 2*dot (z2 dropped: rank-invariant per row)
    const float* rp = ws + r * 256 + w * 32 + 4 * g;
    float4 rv0 = *reinterpret_cast<const float4*>(rp);
    float4 rv1 = *reinterpret_cast<const float4*>(rp + 8);
    float4 rv2 = *reinterpret_cast<const float4*>(rp + 16);
    float4 rv3 = *reinterpret_cast<const float4*>(rp + 24);
    float r2v[16] = {rv0.x, rv0.y, rv0.z, rv0.w, rv1.x, rv1.y, rv1.z, rv1.w,
                     rv2.x, rv2.y, rv2.z, rv2.w, rv3.x, rv3.y, rv3.z, rv3.w};
    const int pb = r << 4;
#pragma unroll
    for (int i = 0; i < 16; ++i) {
      float s0 = fmaf(-2.f, a0[i], r2v[i]);
      float s1 = fmaf(-2.f, a1[i], r2v[i]);
      if (s0 < best0) { best0 = s0; bp0 = pb + i; }
      if (s1 < best1) { best1 = s1; bp1 = pb + i; }
    }
    __syncthreads();   // all reads done before next round's stage overwrites
  }

  // decode packed (round,i) -> global k (ascending-k tie-order preserved)
  int bk0, bk1;
  {
    int rr = bp0 >> 4, i = bp0 & 15;
    bk0 = rr * 256 + w * 32 + (i & 3) + 8 * (i >> 2) + 4 * g;
    rr = bp1 >> 4; i = bp1 & 15;
    bk1 = rr * 256 + w * 32 + (i & 3) + 8 * (i >> 2) + 4 * g;
  }
  // merge the two g-halves (same rows, disjoint codes)
  {
    float ob = __shfl_xor(best0, 32, 64);
    int   ok = __shfl_xor(bk0, 32, 64);
    if (ob < best0 || (ob == best0 && ok < bk0)) { best0 = ob; bk0 = ok; }
    ob = __shfl_xor(best1, 32, 64);
    ok = __shfl_xor(bk1, 32, 64);
    if (ob < best1 || (ob == best1 && ok < bk1)) { best1 = ob; bk1 = ok; }
  }

  // cross-wave merge: 8 tile-waves x 64 rows
  float* fbuf = reinterpret_cast<float*>(lds);          // [8][64]  2KB
  int*   kbuf = reinterpret_cast<int*>(lds + 2048);     // [8][64]  2KB
  int*   ibuf = reinterpret_cast<int*>(lds + 4096);     // [64]
  if (l < 32) {
    fbuf[w * 64 + c]      = best0;  kbuf[w * 64 + c]      = bk0;
    fbuf[w * 64 + 32 + c] = best1;  kbuf[w * 64 + 32 + c] = bk1;
  }
  __syncthreads();

  if (tid < 64) {
    float bb = fbuf[tid];
    int   kk = kbuf[tid];
#pragma unroll
    for (int ww = 1; ww < 8; ++ww) {
      float b2 = fbuf[ww * 64 + tid];
      int   k2 = kbuf[ww * 64 + tid];
      if (b2 < bb || (b2 == bb && k2 < kk)) { bb = b2; kk = k2; }
    }
    ibuf[tid] = kk;
    out[NQ + 2 + rowbase + tid] = (float)kk;
  }
  __syncthreads();

  // gather + losses: 8 threads per row (8 f32 each)
  {
    const int row_l = tid >> 3, seg = tid & 7;
    const int idx  = ibuf[row_l];
    const int grow = rowbase + row_l;
    const float4* qp = reinterpret_cast<const float4*>(cb + (size_t)idx * D_DIM + seg * 8);
    const float4* zp = reinterpret_cast<const float4*>(z + (size_t)grow * D_DIM + seg * 8);
    float4*       op = reinterpret_cast<float4*>(out + (size_t)grow * D_DIM + seg * 8);
    float lp = 0.f;
#pragma unroll
    for (int cc = 0; cc < 2; ++cc) {
      float4 qv = qp[cc], zv = zp[cc];
      op[cc] = qv;
      float dx = zv.x - qv.x, dy = zv.y - qv.y;
      float dz = zv.z - qv.z, dw = zv.w - qv.w;
      lp += (dx * dx + dy * dy) + (dz * dz + dw * dw);
    }
#pragma unroll
    for (int off = 32; off > 0; off >>= 1) lp += __shfl_down(lp, off, 64);
    if (l == 0) atomicAdd(ws + WS_LOSS, lp);
  }
}

// ------------------------------------------------- fallback (proven R4 kernel)
__global__ __launch_bounds__(512, 2) void vq_main_reg(const float* __restrict__ z,
                                                      const float* __restrict__ cb,
                                                      float* __restrict__ ws,
                                                      float* __restrict__ out) {
  __shared__ __attribute__((aligned(16))) unsigned char lds[65536];
  const int tid = threadIdx.x;
  const int w = tid >> 6, l = tid & 63;
  const int rg = w >> 1, sp = w & 1;
  const int c = l & 31, g = l >> 5;
  const int rowbase = blockIdx.x * 128;
  const int myrow = rowbase + rg * 32 + c;

  bf16x8 zh[4], zl[4];
#pragma unroll
  for (int s = 0; s < 4; ++s) {
    const float* zp = z + (size_t)myrow * D_DIM + 16 * s + 8 * g;
    float4 f0 = *reinterpret_cast<const float4*>(zp);
    float4 f1 = *reinterpret_cast<const float4*>(zp + 4);
    float xs[8] = {f0.x, f0.y, f0.z, f0.w, f1.x, f1.y, f1.z, f1.w};
#pragma unroll
    for (int j = 0; j < 8; ++j) {
      __bf16 h = (__bf16)xs[j];
      zh[s][j] = h; zl[s][j] = (__bf16)(xs[j] - (float)h);
    }
  }
  const int st_t01 = tid >> 8;
  const int st_c   = (tid >> 3) & 31;
  const int st_ch  = tid & 7;
  const unsigned st_off = (unsigned)(st_t01 * 16384 + st_ch * 512 + st_c * 16);
  const float* st_g = cb + (size_t)(st_t01 * 32 + st_c) * D_DIM + st_ch * 8;

  float best = FLT_MAX;
  int   bidx = 0;
  float4 p0 = *reinterpret_cast<const float4*>(st_g);
  float4 p1 = *reinterpret_cast<const float4*>(st_g + 4);
  {
    float xs[8] = {p0.x, p0.y, p0.z, p0.w, p1.x, p1.y, p1.z, p1.w};
    bf16x8 hi, lo;
#pragma unroll
    for (int j = 0; j < 8; ++j) {
      __bf16 h = (__bf16)xs[j];
      hi[j] = h; lo[j] = (__bf16)(xs[j] - (float)h);
    }
    *reinterpret_cast<bf16x8*>(lds + st_off)        = hi;
    *reinterpret_cast<bf16x8*>(lds + st_off + 8192) = lo;
  }
  __syncthreads();
  const unsigned rd_base = (unsigned)(sp * 16384 + c * 16);
  for (int r = 0; r < 128; ++r) {
    const int buf = r & 1;
    if (r < 127) {
      const float* gp = st_g + (size_t)(r + 1) * (64 * D_DIM);
      p0 = *reinterpret_cast<const float4*>(gp);
      p1 = *reinterpret_cast<const float4*>(gp + 4);
    }
    const unsigned b0 = (unsigned)buf * 32768u + rd_base;
    bf16x8 ch[4], cl[4];
#pragma unroll
    for (int s = 0; s < 4; ++s) {
      unsigned off = b0 + (unsigned)((2 * s + g) * 512);
      ch[s] = *reinterpret_cast<const bf16x8*>(lds + off);
      cl[s] = *reinterpret_cast<const bf16x8*>(lds + off + 8192);
    }
    f32x16 acc;
#pragma unroll
    for (int i = 0; i < 16; ++i) acc[i] = 0.f;
#pragma unroll
    for (int s = 0; s < 4; ++s) {
      acc = __builtin_amdgcn_mfma_f32_32x32x16_bf16(ch[s], zh[s], acc, 0, 0, 0);
      acc = __builtin_amdgcn_mfma_f32_32x32x16_bf16(ch[s], zl[s], acc, 0, 0, 0);
      acc = __builtin_amdgcn_mfma_f32_32x32x16_bf16(cl[s], zh[s], acc, 0, 0, 0);
    }
    const int tb = (2 * r + sp) * 32 + 4 * g;
#pragma unroll
    for (int q = 0; q < 4; ++q) {
      float4 rv = *reinterpret_cast<const float4*>(ws + tb + 8 * q);
      float ra[4] = {rv.x, rv.y, rv.z, rv.w};
#pragma unroll
      for (int j = 0; j < 4; ++j) {
        float sc = fmaf(-2.f, acc[4 * q + j], ra[j]);
        int kg = tb + 8 * q + j;
        if (sc < best) { best = sc; bidx = kg; }
      }
    }
    if (r < 127) {
      float xs[8] = {p0.x, p0.y, p0.z, p0.w, p1.x, p1.y, p1.z, p1.w};
      bf16x8 hi, lo;
#pragma unroll
      for (int j = 0; j < 8; ++j) {
        __bf16 h = (__bf16)xs[j];
        hi[j] = h; lo[j] = (__bf16)(xs[j] - (float)h);
      }
      unsigned wo = (unsigned)(buf ^ 1) * 32768u + st_off;
      *reinterpret_cast<bf16x8*>(lds + wo)        = hi;
      *reinterpret_cast<bf16x8*>(lds + wo + 8192) = lo;
    }
    __syncthreads();
  }
  {
    float ob = __shfl_xor(best, 32, 64);
    int   oi = __shfl_xor(bidx, 32, 64);
    if (ob < best || (ob == best && oi < bidx)) { best = ob; bidx = oi; }
  }
  float* mf  = reinterpret_cast<float*>(lds);
  int*   mi  = reinterpret_cast<int*>(lds + 1024);
  int*   mix = reinterpret_cast<int*>(lds + 2048);
  if (l < 32) { mf[w * 32 + c] = best; mi[w * 32 + c] = bidx; }
  __syncthreads();
  if (tid < 128) {
    int rgg = tid >> 5, rl = tid & 31;
    float b0 = mf[(2 * rgg) * 32 + rl];     int i0 = mi[(2 * rgg) * 32 + rl];
    float b1 = mf[(2 * rgg + 1) * 32 + rl]; int i1 = mi[(2 * rgg + 1) * 32 + rl];
    int idx = (b1 < b0 || (b1 == b0 && i1 < i0)) ? i1 : i0;
    mix[tid] = idx;
    out[NQ + 2 + rowbase + tid] = (float)idx;
  }
  __syncthreads();
  {
    const int row_l = tid >> 2, seg = tid & 3;
    const int idx  = mix[row_l];
    const int grow = rowbase + row_l;
    const float4* qp = reinterpret_cast<const float4*>(cb + (size_t)idx * D_DIM + seg * 16);
    const float4* zp = reinterpret_cast<const float4*>(z + (size_t)grow * D_DIM + seg * 16);
    float4*       op = reinterpret_cast<float4*>(out + (size_t)grow * D_DIM + seg * 16);
    float lp = 0.f;
#pragma unroll
    for (int cc = 0; cc < 4; ++cc) {
      float4 qv = qp[cc], zv = zp[cc];
      op[cc] = qv;
      float dx = zv.x - qv.x, dy = zv.y - qv.y;
      float dz = zv.z - qv.z, dw = zv.w - qv.w;
      lp += (dx * dx + dy * dy) + (dz * dz + dw * dw);
    }
#pragma unroll
    for (int off = 32; off > 0; off >>= 1) lp += __shfl_down(lp, off, 64);
    if (l == 0) atomicAdd(ws + WS_LOSS, lp);
  }
}

// ------------------------------------------------------------ finalize kernel
__global__ void vq_fin(const float* __restrict__ ws, float* __restrict__ out) {
  float mm = ws[WS_LOSS] * (1.0f / (float)(N_ROWS * D_DIM));
  out[NQ]     = mm;
  out[NQ + 1] = mm;
}

// -------------------------------------------------------------------- launch
extern "C" void kernel_launch(void* const* d_in, const int* in_sizes, int n_in,
                              void* d_out, int out_size, void* d_ws, size_t ws_size,
                              hipStream_t stream) {
  (void)in_sizes; (void)n_in; (void)out_size;
  const float* z  = (const float*)d_in[0];
  const float* cb = (const float*)d_in[1];
  float* out = (float*)d_out;
  float* ws  = (float*)d_ws;

  vq_prep<<<K_CB / 256, 256, 0, stream>>>(cb, ws);
  if (ws_size >= WS_NEED) {
    vq_split<<<256, 256, 0, stream>>>(cb, ws);
    vq_mfma8<<<N_ROWS / 64, 512, 0, stream>>>(z, cb, ws, out);
  } else {
    vq_main_reg<<<N_ROWS / 128, 512, 0, stream>>>(z, cb, ws, out);
  }
  vq_fin<<<1, 1, 0, stream>>>(ws, out);
}

// Round 9
// 139.783 us; speedup vs baseline: 1.1297x; 1.1297x over previous
//
#include <hip/hip_runtime.h>
#include <cfloat>

// VQ-VAE nearest-codebook via bf16x3 split MFMA, v5 "global-direct":
//   - pre-split codebook (hi/lo bf16) in ws (L2-resident, 2 MB)
//   - NO LDS staging, NO main-loop barriers: code fragments load straight
//     from L2 into registers; next-round loads issue after the MFMA cluster
//     (WAR on same regs) and their latency hides under the epilogue VALU.
//   - 512 thr = 8 waves; wave w = code-tile w (32 codes/round); 4 row-accs
//     (128 rows/block, grid 256 = 1 block/CU, 2 waves/SIMD, free-running).
// d_out (f32): [0,NQ) quantized | [NQ] vq_loss | [NQ+1] commitment | [NQ+2,+N) idx
// d_ws  (f32): [0,K) r2 | [K] loss | [8448...) split codebook (2 MB)

typedef __bf16 bf16x8 __attribute__((ext_vector_type(8)));
typedef float  f32x16 __attribute__((ext_vector_type(16)));

constexpr int N_ROWS = 32768;
constexpr int K_CB   = 8192;
constexpr int D_DIM  = 64;
constexpr size_t NQ  = (size_t)N_ROWS * D_DIM;
constexpr int WS_LOSS = K_CB;
constexpr size_t WS_SPLIT_F   = 8448;
constexpr size_t SPLIT_BYTES  = (size_t)K_CB * D_DIM * 4;   // 2 MB
constexpr size_t WS_NEED      = WS_SPLIT_F * 4 + SPLIT_BYTES;
constexpr int NROUND = K_CB / 256;                          // 32 rounds of 256 codes

// ---------------------------------------------------------------- prep: r2
__global__ __launch_bounds__(256) void vq_prep(const float* __restrict__ cb,
                                               float* __restrict__ ws) {
  const int k = blockIdx.x * 256 + threadIdx.x;
  if (k == 0) ws[WS_LOSS] = 0.0f;
  const float4* p = reinterpret_cast<const float4*>(cb) + (size_t)k * 16;
  float s0 = 0.f, s1 = 0.f, s2 = 0.f, s3 = 0.f;
#pragma unroll
  for (int j = 0; j < 16; ++j) {
    float4 v = p[j];
    s0 = fmaf(v.x, v.x, s0); s1 = fmaf(v.y, v.y, s1);
    s2 = fmaf(v.z, v.z, s2); s3 = fmaf(v.w, v.w, s3);
  }
  ws[k] = (s0 + s1) + (s2 + s3);
}

// ------------------------------------------------- prep: split codebook in ws
// Round r (256 codes) -> 64KB block: t(=k>>5&7)*8192 + h*4096 + ch*512 + c*16.
__global__ __launch_bounds__(256) void vq_split(const float* __restrict__ cb,
                                                float* __restrict__ ws) {
  const int u  = blockIdx.x * 256 + threadIdx.x;   // 65536 threads
  const int k  = u >> 3, ch = u & 7;
  const int r  = k >> 8, t = (k >> 5) & 7, c = k & 31;
  const float* src = cb + (size_t)k * D_DIM + ch * 8;
  float4 f0 = *reinterpret_cast<const float4*>(src);
  float4 f1 = *reinterpret_cast<const float4*>(src + 4);
  float xs[8] = {f0.x, f0.y, f0.z, f0.w, f1.x, f1.y, f1.z, f1.w};
  bf16x8 hi, lo;
#pragma unroll
  for (int j = 0; j < 8; ++j) {
    __bf16 h = (__bf16)xs[j];
    hi[j] = h;
    lo[j] = (__bf16)(xs[j] - (float)h);
  }
  char* base = reinterpret_cast<char*>(ws + WS_SPLIT_F) +
               (size_t)r * 65536 + (size_t)t * 8192 + (size_t)ch * 512 + (size_t)c * 16;
  *reinterpret_cast<bf16x8*>(base)        = hi;
  *reinterpret_cast<bf16x8*>(base + 4096) = lo;
}

// ---------------------------------------------------------------- main kernel
__global__ __launch_bounds__(512, 2) void vq_gd(const float* __restrict__ z,
                                                const float* __restrict__ cb,
                                                float* __restrict__ ws,
                                                float* __restrict__ out) {
  __shared__ __attribute__((aligned(16))) unsigned char lds[12288];

  const int tid = threadIdx.x;
  const int w = tid >> 6, l = tid & 63;
  const int c = l & 31, g = l >> 5;
  const int rowbase = blockIdx.x * 128;

  // --- z fragments: 4 rowsets x 4 k-steps, hi/lo split, registers forever ---
  bf16x8 zh[4][4], zl[4][4];
#pragma unroll
  for (int q = 0; q < 4; ++q) {
    const float* zr = z + (size_t)(rowbase + q * 32 + c) * D_DIM + 8 * g;
#pragma unroll
    for (int s = 0; s < 4; ++s) {
      float4 f0 = *reinterpret_cast<const float4*>(zr + 16 * s);
      float4 f1 = *reinterpret_cast<const float4*>(zr + 16 * s + 4);
      float xs[8] = {f0.x, f0.y, f0.z, f0.w, f1.x, f1.y, f1.z, f1.w};
#pragma unroll
      for (int j = 0; j < 8; ++j) {
        __bf16 h = (__bf16)xs[j];
        zh[q][s][j] = h;
        zl[q][s][j] = (__bf16)(xs[j] - (float)h);
      }
    }
  }

  // code-fragment pointers for my tile (lane-resolved): hi at +s*1024, lo +4096
  const char* hp = reinterpret_cast<const char*>(ws + WS_SPLIT_F) +
                   (size_t)w * 8192 + (size_t)g * 512 + (size_t)c * 16;
  const char* lq = hp + 4096;

  // prologue: round-0 fragments
  bf16x8 fh[4], fl[4];
#pragma unroll
  for (int s = 0; s < 4; ++s) {
    fh[s] = *reinterpret_cast<const bf16x8*>(hp + s * 1024);
    fl[s] = *reinterpret_cast<const bf16x8*>(lq + s * 1024);
  }

  float best[4];
  int   bpack[4];
#pragma unroll
  for (int q = 0; q < 4; ++q) { best[q] = FLT_MAX; bpack[q] = 0; }

  for (int r = 0; r < NROUND; ++r) {
    f32x16 a0, a1, a2, a3;
#pragma unroll
    for (int i = 0; i < 16; ++i) { a0[i] = 0.f; a1[i] = 0.f; a2[i] = 0.f; a3[i] = 0.f; }

    __builtin_amdgcn_s_setprio(1);
#pragma unroll
    for (int s = 0; s < 4; ++s) {
      a0 = __builtin_amdgcn_mfma_f32_32x32x16_bf16(fh[s], zh[0][s], a0, 0, 0, 0);
      a1 = __builtin_amdgcn_mfma_f32_32x32x16_bf16(fh[s], zh[1][s], a1, 0, 0, 0);
      a2 = __builtin_amdgcn_mfma_f32_32x32x16_bf16(fh[s], zh[2][s], a2, 0, 0, 0);
      a3 = __builtin_amdgcn_mfma_f32_32x32x16_bf16(fh[s], zh[3][s], a3, 0, 0, 0);
      a0 = __builtin_amdgcn_mfma_f32_32x32x16_bf16(fh[s], zl[0][s], a0, 0, 0, 0);
      a1 = __builtin_amdgcn_mfma_f32_32x32x16_bf16(fh[s], zl[1][s], a1, 0, 0, 0);
      a2 = __builtin_amdgcn_mfma_f32_32x32x16_bf16(fh[s], zl[2][s], a2, 0, 0, 0);
      a3 = __builtin_amdgcn_mfma_f32_32x32x16_bf16(fh[s], zl[3][s], a3, 0, 0, 0);
      a0 = __builtin_amdgcn_mfma_f32_32x32x16_bf16(fl[s], zh[0][s], a0, 0, 0, 0);
      a1 = __builtin_amdgcn_mfma_f32_32x32x16_bf16(fl[s], zh[1][s], a1, 0, 0, 0);
      a2 = __builtin_amdgcn_mfma_f32_32x32x16_bf16(fl[s], zh[2][s], a2, 0, 0, 0);
      a3 = __builtin_amdgcn_mfma_f32_32x32x16_bf16(fl[s], zh[3][s], a3, 0, 0, 0);
    }
    __builtin_amdgcn_s_setprio(0);

    // issue next-round fragment loads NOW (WAR: after MFMAs read fh/fl);
    // their latency hides under the epilogue below.
    if (r < NROUND - 1) {
      hp += 65536; lq += 65536;
#pragma unroll
      for (int s = 0; s < 4; ++s) {
        fh[s] = *reinterpret_cast<const bf16x8*>(hp + s * 1024);
        fl[s] = *reinterpret_cast<const bf16x8*>(lq + s * 1024);
      }
    }

    // epilogue: sc = r2[k] - 2*dot (z2 dropped: rank-invariant per row)
    const float* rp = ws + r * 256 + w * 32 + 4 * g;
    float4 rv0 = *reinterpret_cast<const float4*>(rp);
    float4 rv1 = *reinterpret_cast<const float4*>(rp + 8);
    float4 rv2 = *reinterpret_cast<const float4*>(rp + 16);
    float4 rv3 = *reinterpret_cast<const float4*>(rp + 24);
    float r2v[16] = {rv0.x, rv0.y, rv0.z, rv0.w, rv1.x, rv1.y, rv1.z, rv1.w,
                     rv2.x, rv2.y, rv2.z, rv2.w, rv3.x, rv3.y, rv3.z, rv3.w};
    const int pb = r << 4;
#pragma unroll
    for (int i = 0; i < 16; ++i) {
      float s0 = fmaf(-2.f, a0[i], r2v[i]);
      float s1 = fmaf(-2.f, a1[i], r2v[i]);
      float s2 = fmaf(-2.f, a2[i], r2v[i]);
      float s3 = fmaf(-2.f, a3[i], r2v[i]);
      if (s0 < best[0]) { best[0] = s0; bpack[0] = pb + i; }
      if (s1 < best[1]) { best[1] = s1; bpack[1] = pb + i; }
      if (s2 < best[2]) { best[2] = s2; bpack[2] = pb + i; }
      if (s3 < best[3]) { best[3] = s3; bpack[3] = pb + i; }
    }
  }

  // --- decode packed (round,i) -> global k, then exact-tie merges (R5-proven) ---
  int bk[4];
#pragma unroll
  for (int q = 0; q < 4; ++q) {
    int rr = bpack[q] >> 4, i = bpack[q] & 15;
    int cid = (i & 3) + 8 * (i >> 2) + 4 * g;
    bk[q] = rr * 256 + w * 32 + cid;
  }
#pragma unroll
  for (int q = 0; q < 4; ++q) {
    float ob = __shfl_xor(best[q], 32, 64);
    int   ok = __shfl_xor(bk[q], 32, 64);
    if (ob < best[q] || (ob == best[q] && ok < bk[q])) { best[q] = ob; bk[q] = ok; }
  }

  float* fbuf = reinterpret_cast<float*>(lds);          // [8 tiles][128 rows]
  int*   kbuf = reinterpret_cast<int*>(lds + 4096);     // [8][128]
  int*   ibuf = reinterpret_cast<int*>(lds + 8192);     // [128]
  if (l < 32) {
#pragma unroll
    for (int q = 0; q < 4; ++q) {
      fbuf[w * 128 + q * 32 + l] = best[q];
      kbuf[w * 128 + q * 32 + l] = bk[q];
    }
  }
  __syncthreads();

  if (tid < 128) {
    float bb = fbuf[tid];
    int   kk = kbuf[tid];
#pragma unroll
    for (int ww = 1; ww < 8; ++ww) {
      float b2 = fbuf[ww * 128 + tid];
      int   k2 = kbuf[ww * 128 + tid];
      if (b2 < bb || (b2 == bb && k2 < kk)) { bb = b2; kk = k2; }
    }
    ibuf[tid] = kk;
    out[NQ + 2 + rowbase + tid] = (float)kk;
  }
  __syncthreads();

  // --- gather + losses: 4 threads per row ---
  {
    const int row_l = tid >> 2, seg = tid & 3;
    const int idx  = ibuf[row_l];
    const int grow = rowbase + row_l;
    const float4* qp = reinterpret_cast<const float4*>(cb + (size_t)idx * D_DIM + seg * 16);
    const float4* zp = reinterpret_cast<const float4*>(z + (size_t)grow * D_DIM + seg * 16);
    float4*       op = reinterpret_cast<float4*>(out + (size_t)grow * D_DIM + seg * 16);
    float lp = 0.f;
#pragma unroll
    for (int cc = 0; cc < 4; ++cc) {
      float4 qv = qp[cc], zv = zp[cc];
      op[cc] = qv;
      float dx = zv.x - qv.x, dy = zv.y - qv.y;
      float dz = zv.z - qv.z, dw = zv.w - qv.w;
      lp += (dx * dx + dy * dy) + (dz * dz + dw * dw);
    }
#pragma unroll
    for (int off = 32; off > 0; off >>= 1) lp += __shfl_down(lp, off, 64);
    if (l == 0) atomicAdd(ws + WS_LOSS, lp);
  }
}

// ------------------------------------------------- fallback (proven R4 kernel)
__global__ __launch_bounds__(512, 2) void vq_main_reg(const float* __restrict__ z,
                                                      const float* __restrict__ cb,
                                                      float* __restrict__ ws,
                                                      float* __restrict__ out) {
  __shared__ __attribute__((aligned(16))) unsigned char lds[65536];
  const int tid = threadIdx.x;
  const int w = tid >> 6, l = tid & 63;
  const int rg = w >> 1, sp = w & 1;
  const int c = l & 31, g = l >> 5;
  const int rowbase = blockIdx.x * 128;
  const int myrow = rowbase + rg * 32 + c;

  bf16x8 zh[4], zl[4];
#pragma unroll
  for (int s = 0; s < 4; ++s) {
    const float* zp = z + (size_t)myrow * D_DIM + 16 * s + 8 * g;
    float4 f0 = *reinterpret_cast<const float4*>(zp);
    float4 f1 = *reinterpret_cast<const float4*>(zp + 4);
    float xs[8] = {f0.x, f0.y, f0.z, f0.w, f1.x, f1.y, f1.z, f1.w};
#pragma unroll
    for (int j = 0; j < 8; ++j) {
      __bf16 h = (__bf16)xs[j];
      zh[s][j] = h; zl[s][j] = (__bf16)(xs[j] - (float)h);
    }
  }
  const int st_t01 = tid >> 8;
  const int st_c   = (tid >> 3) & 31;
  const int st_ch  = tid & 7;
  const unsigned st_off = (unsigned)(st_t01 * 16384 + st_ch * 512 + st_c * 16);
  const float* st_g = cb + (size_t)(st_t01 * 32 + st_c) * D_DIM + st_ch * 8;

  float best = FLT_MAX;
  int   bidx = 0;
  float4 p0 = *reinterpret_cast<const float4*>(st_g);
  float4 p1 = *reinterpret_cast<const float4*>(st_g + 4);
  {
    float xs[8] = {p0.x, p0.y, p0.z, p0.w, p1.x, p1.y, p1.z, p1.w};
    bf16x8 hi, lo;
#pragma unroll
    for (int j = 0; j < 8; ++j) {
      __bf16 h = (__bf16)xs[j];
      hi[j] = h; lo[j] = (__bf16)(xs[j] - (float)h);
    }
    *reinterpret_cast<bf16x8*>(lds + st_off)        = hi;
    *reinterpret_cast<bf16x8*>(lds + st_off + 8192) = lo;
  }
  __syncthreads();
  const unsigned rd_base = (unsigned)(sp * 16384 + c * 16);
  for (int r = 0; r < 128; ++r) {
    const int buf = r & 1;
    if (r < 127) {
      const float* gp = st_g + (size_t)(r + 1) * (64 * D_DIM);
      p0 = *reinterpret_cast<const float4*>(gp);
      p1 = *reinterpret_cast<const float4*>(gp + 4);
    }
    const unsigned b0 = (unsigned)buf * 32768u + rd_base;
    bf16x8 ch[4], cl[4];
#pragma unroll
    for (int s = 0; s < 4; ++s) {
      unsigned off = b0 + (unsigned)((2 * s + g) * 512);
      ch[s] = *reinterpret_cast<const bf16x8*>(lds + off);
      cl[s] = *reinterpret_cast<const bf16x8*>(lds + off + 8192);
    }
    f32x16 acc;
#pragma unroll
    for (int i = 0; i < 16; ++i) acc[i] = 0.f;
#pragma unroll
    for (int s = 0; s < 4; ++s) {
      acc = __builtin_amdgcn_mfma_f32_32x32x16_bf16(ch[s], zh[s], acc, 0, 0, 0);
      acc = __builtin_amdgcn_mfma_f32_32x32x16_bf16(ch[s], zl[s], acc, 0, 0, 0);
      acc = __builtin_amdgcn_mfma_f32_32x32x16_bf16(cl[s], zh[s], acc, 0, 0, 0);
    }
    const int tb = (2 * r + sp) * 32 + 4 * g;
#pragma unroll
    for (int q = 0; q < 4; ++q) {
      float4 rv = *reinterpret_cast<const float4*>(ws + tb + 8 * q);
      float ra[4] = {rv.x, rv.y, rv.z, rv.w};
#pragma unroll
      for (int j = 0; j < 4; ++j) {
        float sc = fmaf(-2.f, acc[4 * q + j], ra[j]);
        int kg = tb + 8 * q + j;
        if (sc < best) { best = sc; bidx = kg; }
      }
    }
    if (r < 127) {
      float xs[8] = {p0.x, p0.y, p0.z, p0.w, p1.x, p1.y, p1.z, p1.w};
      bf16x8 hi, lo;
#pragma unroll
      for (int j = 0; j < 8; ++j) {
        __bf16 h = (__bf16)xs[j];
        hi[j] = h; lo[j] = (__bf16)(xs[j] - (float)h);
      }
      unsigned wo = (unsigned)(buf ^ 1) * 32768u + st_off;
      *reinterpret_cast<bf16x8*>(lds + wo)        = hi;
      *reinterpret_cast<bf16x8*>(lds + wo + 8192) = lo;
    }
    __syncthreads();
  }
  {
    float ob = __shfl_xor(best, 32, 64);
    int   oi = __shfl_xor(bidx, 32, 64);
    if (ob < best || (ob == best && oi < bidx)) { best = ob; bidx = oi; }
  }
  float* mf  = reinterpret_cast<float*>(lds);
  int*   mi  = reinterpret_cast<int*>(lds + 1024);
  int*   mix = reinterpret_cast<int*>(lds + 2048);
  if (l < 32) { mf[w * 32 + c] = best; mi[w * 32 + c] = bidx; }
  __syncthreads();
  if (tid < 128) {
    int rgg = tid >> 5, rl = tid & 31;
    float b0 = mf[(2 * rgg) * 32 + rl];     int i0 = mi[(2 * rgg) * 32 + rl];
    float b1 = mf[(2 * rgg + 1) * 32 + rl]; int i1 = mi[(2 * rgg + 1) * 32 + rl];
    int idx = (b1 < b0 || (b1 == b0 && i1 < i0)) ? i1 : i0;
    mix[tid] = idx;
    out[NQ + 2 + rowbase + tid] = (float)idx;
  }
  __syncthreads();
  {
    const int row_l = tid >> 2, seg = tid & 3;
    const int idx  = mix[row_l];
    const int grow = rowbase + row_l;
    const float4* qp = reinterpret_cast<const float4*>(cb + (size_t)idx * D_DIM + seg * 16);
    const float4* zp = reinterpret_cast<const float4*>(z + (size_t)grow * D_DIM + seg * 16);
    float4*       op = reinterpret_cast<float4*>(out + (size_t)grow * D_DIM + seg * 16);
    float lp = 0.f;
#pragma unroll
    for (int cc = 0; cc < 4; ++cc) {
      float4 qv = qp[cc], zv = zp[cc];
      op[cc] = qv;
      float dx = zv.x - qv.x, dy = zv.y - qv.y;
      float dz = zv.z - qv.z, dw = zv.w - qv.w;
      lp += (dx * dx + dy * dy) + (dz * dz + dw * dw);
    }
#pragma unroll
    for (int off = 32; off > 0; off >>= 1) lp += __shfl_down(lp, off, 64);
    if (l == 0) atomicAdd(ws + WS_LOSS, lp);
  }
}

// ------------------------------------------------------------ finalize kernel
__global__ void vq_fin(const float* __restrict__ ws, float* __restrict__ out) {
  float mm = ws[WS_LOSS] * (1.0f / (float)(N_ROWS * D_DIM));
  out[NQ]     = mm;
  out[NQ + 1] = mm;
}

// -------------------------------------------------------------------- launch
extern "C" void kernel_launch(void* const* d_in, const int* in_sizes, int n_in,
                              void* d_out, int out_size, void* d_ws, size_t ws_size,
                              hipStream_t stream) {
  (void)in_sizes; (void)n_in; (void)out_size;
  const float* z  = (const float*)d_in[0];
  const float* cb = (const float*)d_in[1];
  float* out = (float*)d_out;
  float* ws  = (float*)d_ws;

  vq_prep<<<K_CB / 256, 256, 0, stream>>>(cb, ws);
  if (ws_size >= WS_NEED) {
    vq_split<<<256, 256, 0, stream>>>(cb, ws);
    vq_gd<<<N_ROWS / 128, 512, 0, stream>>>(z, cb, ws, out);
  } else {
    vq_main_reg<<<N_ROWS / 128, 512, 0, stream>>>(z, cb, ws, out);
  }
  vq_fin<<<1, 1, 0, stream>>>(ws, out);
}

// Round 10
// 129.442 us; speedup vs baseline: 1.2199x; 1.0799x over previous
//
#include <hip/hip_runtime.h>
#include <cfloat>

// VQ-VAE nearest-codebook via bf16x3 split MFMA, v6 "C-init + cheap argmax":
//   - prep stores r2n[k] = -||e_k||^2 / 2 ; accs are C-initialized with r2n
//     so acc = dot - r2/2 and the winner is argmax(acc)  (rank-exact).
//   - per-round epilogue: tree-fmax 16->1 per acc, descending equality scan
//     for first-i (bit-exact), single conditional global update (r<<4|i).
//   - global-direct fragment loads (L2-resident split codebook), no barriers.
// d_out (f32): [0,NQ) quantized | [NQ] vq_loss | [NQ+1] commitment | [NQ+2,+N) idx
// d_ws  (f32): [0,K) r2n | [K] loss | [8448...) split codebook (2 MB)

typedef __bf16 bf16x8 __attribute__((ext_vector_type(8)));
typedef float  f32x16 __attribute__((ext_vector_type(16)));

constexpr int N_ROWS = 32768;
constexpr int K_CB   = 8192;
constexpr int D_DIM  = 64;
constexpr size_t NQ  = (size_t)N_ROWS * D_DIM;
constexpr int WS_LOSS = K_CB;
constexpr size_t WS_SPLIT_F   = 8448;
constexpr size_t SPLIT_BYTES  = (size_t)K_CB * D_DIM * 4;   // 2 MB
constexpr size_t WS_NEED      = WS_SPLIT_F * 4 + SPLIT_BYTES;
constexpr int NROUND = K_CB / 256;                          // 32 rounds of 256 codes

// ---------------------------------------------------------------- prep: r2n
__global__ __launch_bounds__(256) void vq_prep(const float* __restrict__ cb,
                                               float* __restrict__ ws) {
  const int k = blockIdx.x * 256 + threadIdx.x;
  if (k == 0) ws[WS_LOSS] = 0.0f;
  const float4* p = reinterpret_cast<const float4*>(cb) + (size_t)k * 16;
  float s0 = 0.f, s1 = 0.f, s2 = 0.f, s3 = 0.f;
#pragma unroll
  for (int j = 0; j < 16; ++j) {
    float4 v = p[j];
    s0 = fmaf(v.x, v.x, s0); s1 = fmaf(v.y, v.y, s1);
    s2 = fmaf(v.z, v.z, s2); s3 = fmaf(v.w, v.w, s3);
  }
  ws[k] = -0.5f * ((s0 + s1) + (s2 + s3));   // r2n = -r2/2
}

// ------------------------------------------------- prep: split codebook in ws
// Round r (256 codes) -> 64KB block: t(=k>>5&7)*8192 + h*4096 + ch*512 + c*16.
__global__ __launch_bounds__(256) void vq_split(const float* __restrict__ cb,
                                                float* __restrict__ ws) {
  const int u  = blockIdx.x * 256 + threadIdx.x;   // 65536 threads
  const int k  = u >> 3, ch = u & 7;
  const int r  = k >> 8, t = (k >> 5) & 7, c = k & 31;
  const float* src = cb + (size_t)k * D_DIM + ch * 8;
  float4 f0 = *reinterpret_cast<const float4*>(src);
  float4 f1 = *reinterpret_cast<const float4*>(src + 4);
  float xs[8] = {f0.x, f0.y, f0.z, f0.w, f1.x, f1.y, f1.z, f1.w};
  bf16x8 hi, lo;
#pragma unroll
  for (int j = 0; j < 8; ++j) {
    __bf16 h = (__bf16)xs[j];
    hi[j] = h;
    lo[j] = (__bf16)(xs[j] - (float)h);
  }
  char* base = reinterpret_cast<char*>(ws + WS_SPLIT_F) +
               (size_t)r * 65536 + (size_t)t * 8192 + (size_t)ch * 512 + (size_t)c * 16;
  *reinterpret_cast<bf16x8*>(base)        = hi;
  *reinterpret_cast<bf16x8*>(base + 4096) = lo;
}

// ---------------------------------------------------------------- main kernel
__global__ __launch_bounds__(512, 2) void vq_gd2(const float* __restrict__ z,
                                                 const float* __restrict__ cb,
                                                 float* __restrict__ ws,
                                                 float* __restrict__ out) {
  __shared__ __attribute__((aligned(16))) unsigned char lds[12288];

  const int tid = threadIdx.x;
  const int w = tid >> 6, l = tid & 63;
  const int c = l & 31, g = l >> 5;
  const int rowbase = blockIdx.x * 128;

  // --- z fragments: 4 rowsets x 4 k-steps, hi/lo split, registers forever ---
  bf16x8 zh[4][4], zl[4][4];
#pragma unroll
  for (int q = 0; q < 4; ++q) {
    const float* zr = z + (size_t)(rowbase + q * 32 + c) * D_DIM + 8 * g;
#pragma unroll
    for (int s = 0; s < 4; ++s) {
      float4 f0 = *reinterpret_cast<const float4*>(zr + 16 * s);
      float4 f1 = *reinterpret_cast<const float4*>(zr + 16 * s + 4);
      float xs[8] = {f0.x, f0.y, f0.z, f0.w, f1.x, f1.y, f1.z, f1.w};
#pragma unroll
      for (int j = 0; j < 8; ++j) {
        __bf16 h = (__bf16)xs[j];
        zh[q][s][j] = h;
        zl[q][s][j] = (__bf16)(xs[j] - (float)h);
      }
    }
  }

  // code-fragment pointers for my tile: hi at +s*1024, lo +4096
  const char* hp = reinterpret_cast<const char*>(ws + WS_SPLIT_F) +
                   (size_t)w * 8192 + (size_t)g * 512 + (size_t)c * 16;
  const char* lq = hp + 4096;
  const float* rp = ws + w * 32 + 4 * g;

  // prologue: round-0 fragments + r2n
  bf16x8 fh[4], fl[4];
#pragma unroll
  for (int s = 0; s < 4; ++s) {
    fh[s] = *reinterpret_cast<const bf16x8*>(hp + s * 1024);
    fl[s] = *reinterpret_cast<const bf16x8*>(lq + s * 1024);
  }
  float4 rv0 = *reinterpret_cast<const float4*>(rp);
  float4 rv1 = *reinterpret_cast<const float4*>(rp + 8);
  float4 rv2 = *reinterpret_cast<const float4*>(rp + 16);
  float4 rv3 = *reinterpret_cast<const float4*>(rp + 24);

  float gbest[4];
  int   bpack[4];   // (round<<4) | i
#pragma unroll
  for (int q = 0; q < 4; ++q) { gbest[q] = -FLT_MAX; bpack[q] = 0; }

  for (int r = 0; r < NROUND; ++r) {
    // C-init: acc = r2n (same 16 codes for all 4 row-accs)
    f32x16 ainit;
    ainit[0] = rv0.x; ainit[1] = rv0.y; ainit[2]  = rv0.z; ainit[3]  = rv0.w;
    ainit[4] = rv1.x; ainit[5] = rv1.y; ainit[6]  = rv1.z; ainit[7]  = rv1.w;
    ainit[8] = rv2.x; ainit[9] = rv2.y; ainit[10] = rv2.z; ainit[11] = rv2.w;
    ainit[12] = rv3.x; ainit[13] = rv3.y; ainit[14] = rv3.z; ainit[15] = rv3.w;
    f32x16 a0 = ainit, a1 = ainit, a2 = ainit, a3 = ainit;

    __builtin_amdgcn_s_setprio(1);
#pragma unroll
    for (int s = 0; s < 4; ++s) {
      a0 = __builtin_amdgcn_mfma_f32_32x32x16_bf16(fh[s], zh[0][s], a0, 0, 0, 0);
      a1 = __builtin_amdgcn_mfma_f32_32x32x16_bf16(fh[s], zh[1][s], a1, 0, 0, 0);
      a2 = __builtin_amdgcn_mfma_f32_32x32x16_bf16(fh[s], zh[2][s], a2, 0, 0, 0);
      a3 = __builtin_amdgcn_mfma_f32_32x32x16_bf16(fh[s], zh[3][s], a3, 0, 0, 0);
      a0 = __builtin_amdgcn_mfma_f32_32x32x16_bf16(fh[s], zl[0][s], a0, 0, 0, 0);
      a1 = __builtin_amdgcn_mfma_f32_32x32x16_bf16(fh[s], zl[1][s], a1, 0, 0, 0);
      a2 = __builtin_amdgcn_mfma_f32_32x32x16_bf16(fh[s], zl[2][s], a2, 0, 0, 0);
      a3 = __builtin_amdgcn_mfma_f32_32x32x16_bf16(fh[s], zl[3][s], a3, 0, 0, 0);
      a0 = __builtin_amdgcn_mfma_f32_32x32x16_bf16(fl[s], zh[0][s], a0, 0, 0, 0);
      a1 = __builtin_amdgcn_mfma_f32_32x32x16_bf16(fl[s], zh[1][s], a1, 0, 0, 0);
      a2 = __builtin_amdgcn_mfma_f32_32x32x16_bf16(fl[s], zh[2][s], a2, 0, 0, 0);
      a3 = __builtin_amdgcn_mfma_f32_32x32x16_bf16(fl[s], zh[3][s], a3, 0, 0, 0);
    }
    __builtin_amdgcn_s_setprio(0);

    // prefetch next round (WAR after cluster reads; latency hides under epilogue)
    if (r < NROUND - 1) {
      hp += 65536; lq += 65536; rp += 256;
#pragma unroll
      for (int s = 0; s < 4; ++s) {
        fh[s] = *reinterpret_cast<const bf16x8*>(hp + s * 1024);
        fl[s] = *reinterpret_cast<const bf16x8*>(lq + s * 1024);
      }
      rv0 = *reinterpret_cast<const float4*>(rp);
      rv1 = *reinterpret_cast<const float4*>(rp + 8);
      rv2 = *reinterpret_cast<const float4*>(rp + 16);
      rv3 = *reinterpret_cast<const float4*>(rp + 24);
    }

    // epilogue: per acc, tree-max -> first-i equality scan -> global update
    const int pb = r << 4;
#pragma unroll
    for (int q = 0; q < 4; ++q) {
      const f32x16& a = (q == 0) ? a0 : (q == 1) ? a1 : (q == 2) ? a2 : a3;
      float m = a[0];
#pragma unroll
      for (int i = 1; i < 16; ++i) m = fmaxf(m, a[i]);
      int bi = 0;
#pragma unroll
      for (int i = 15; i >= 0; --i) bi = (a[i] == m) ? i : bi;  // smallest i
      bool upd = m > gbest[q];              // strict: earliest round wins
      gbest[q] = upd ? m : gbest[q];
      bpack[q] = upd ? (pb + bi) : bpack[q];
    }
  }

  // --- decode packed (round,i) -> global k, then exact-tie merges (max) ---
  int bk[4];
#pragma unroll
  for (int q = 0; q < 4; ++q) {
    int rr = bpack[q] >> 4, i = bpack[q] & 15;
    int cid = (i & 3) + 8 * (i >> 2) + 4 * g;
    bk[q] = rr * 256 + w * 32 + cid;
  }
#pragma unroll
  for (int q = 0; q < 4; ++q) {
    float ob = __shfl_xor(gbest[q], 32, 64);
    int   ok = __shfl_xor(bk[q], 32, 64);
    if (ob > gbest[q] || (ob == gbest[q] && ok < bk[q])) { gbest[q] = ob; bk[q] = ok; }
  }

  float* fbuf = reinterpret_cast<float*>(lds);          // [8 tiles][128 rows]
  int*   kbuf = reinterpret_cast<int*>(lds + 4096);     // [8][128]
  int*   ibuf = reinterpret_cast<int*>(lds + 8192);     // [128]
  if (l < 32) {
#pragma unroll
    for (int q = 0; q < 4; ++q) {
      fbuf[w * 128 + q * 32 + l] = gbest[q];
      kbuf[w * 128 + q * 32 + l] = bk[q];
    }
  }
  __syncthreads();

  if (tid < 128) {
    float bb = fbuf[tid];
    int   kk = kbuf[tid];
#pragma unroll
    for (int ww = 1; ww < 8; ++ww) {
      float b2 = fbuf[ww * 128 + tid];
      int   k2 = kbuf[ww * 128 + tid];
      if (b2 > bb || (b2 == bb && k2 < kk)) { bb = b2; kk = k2; }
    }
    ibuf[tid] = kk;
    out[NQ + 2 + rowbase + tid] = (float)kk;
  }
  __syncthreads();

  // --- gather + losses: 4 threads per row ---
  {
    const int row_l = tid >> 2, seg = tid & 3;
    const int idx  = ibuf[row_l];
    const int grow = rowbase + row_l;
    const float4* qp = reinterpret_cast<const float4*>(cb + (size_t)idx * D_DIM + seg * 16);
    const float4* zp = reinterpret_cast<const float4*>(z + (size_t)grow * D_DIM + seg * 16);
    float4*       op = reinterpret_cast<float4*>(out + (size_t)grow * D_DIM + seg * 16);
    float lp = 0.f;
#pragma unroll
    for (int cc = 0; cc < 4; ++cc) {
      float4 qv = qp[cc], zv = zp[cc];
      op[cc] = qv;
      float dx = zv.x - qv.x, dy = zv.y - qv.y;
      float dz = zv.z - qv.z, dw = zv.w - qv.w;
      lp += (dx * dx + dy * dy) + (dz * dz + dw * dw);
    }
#pragma unroll
    for (int off = 32; off > 0; off >>= 1) lp += __shfl_down(lp, off, 64);
    if (l == 0) atomicAdd(ws + WS_LOSS, lp);
  }
}

// ------------------------------------------------- fallback (R4-style; adapted
// to r2n semantics: score = r2n + dot, maximize)
__global__ __launch_bounds__(512, 2) void vq_main_reg(const float* __restrict__ z,
                                                      const float* __restrict__ cb,
                                                      float* __restrict__ ws,
                                                      float* __restrict__ out) {
  __shared__ __attribute__((aligned(16))) unsigned char lds[65536];
  const int tid = threadIdx.x;
  const int w = tid >> 6, l = tid & 63;
  const int rg = w >> 1, sp = w & 1;
  const int c = l & 31, g = l >> 5;
  const int rowbase = blockIdx.x * 128;
  const int myrow = rowbase + rg * 32 + c;

  bf16x8 zh[4], zl[4];
#pragma unroll
  for (int s = 0; s < 4; ++s) {
    const float* zp = z + (size_t)myrow * D_DIM + 16 * s + 8 * g;
    float4 f0 = *reinterpret_cast<const float4*>(zp);
    float4 f1 = *reinterpret_cast<const float4*>(zp + 4);
    float xs[8] = {f0.x, f0.y, f0.z, f0.w, f1.x, f1.y, f1.z, f1.w};
#pragma unroll
    for (int j = 0; j < 8; ++j) {
      __bf16 h = (__bf16)xs[j];
      zh[s][j] = h; zl[s][j] = (__bf16)(xs[j] - (float)h);
    }
  }
  const int st_t01 = tid >> 8;
  const int st_c   = (tid >> 3) & 31;
  const int st_ch  = tid & 7;
  const unsigned st_off = (unsigned)(st_t01 * 16384 + st_ch * 512 + st_c * 16);
  const float* st_g = cb + (size_t)(st_t01 * 32 + st_c) * D_DIM + st_ch * 8;

  float best = -FLT_MAX;
  int   bidx = 0;
  float4 p0 = *reinterpret_cast<const float4*>(st_g);
  float4 p1 = *reinterpret_cast<const float4*>(st_g + 4);
  {
    float xs[8] = {p0.x, p0.y, p0.z, p0.w, p1.x, p1.y, p1.z, p1.w};
    bf16x8 hi, lo;
#pragma unroll
    for (int j = 0; j < 8; ++j) {
      __bf16 h = (__bf16)xs[j];
      hi[j] = h; lo[j] = (__bf16)(xs[j] - (float)h);
    }
    *reinterpret_cast<bf16x8*>(lds + st_off)        = hi;
    *reinterpret_cast<bf16x8*>(lds + st_off + 8192) = lo;
  }
  __syncthreads();
  const unsigned rd_base = (unsigned)(sp * 16384 + c * 16);
  for (int r = 0; r < 128; ++r) {
    const int buf = r & 1;
    if (r < 127) {
      const float* gp = st_g + (size_t)(r + 1) * (64 * D_DIM);
      p0 = *reinterpret_cast<const float4*>(gp);
      p1 = *reinterpret_cast<const float4*>(gp + 4);
    }
    const unsigned b0 = (unsigned)buf * 32768u + rd_base;
    bf16x8 ch[4], cl[4];
#pragma unroll
    for (int s = 0; s < 4; ++s) {
      unsigned off = b0 + (unsigned)((2 * s + g) * 512);
      ch[s] = *reinterpret_cast<const bf16x8*>(lds + off);
      cl[s] = *reinterpret_cast<const bf16x8*>(lds + off + 8192);
    }
    f32x16 acc;
#pragma unroll
    for (int i = 0; i < 16; ++i) acc[i] = 0.f;
#pragma unroll
    for (int s = 0; s < 4; ++s) {
      acc = __builtin_amdgcn_mfma_f32_32x32x16_bf16(ch[s], zh[s], acc, 0, 0, 0);
      acc = __builtin_amdgcn_mfma_f32_32x32x16_bf16(ch[s], zl[s], acc, 0, 0, 0);
      acc = __builtin_amdgcn_mfma_f32_32x32x16_bf16(cl[s], zh[s], acc, 0, 0, 0);
    }
    const int tb = (2 * r + sp) * 32 + 4 * g;
#pragma unroll
    for (int q = 0; q < 4; ++q) {
      float4 rv = *reinterpret_cast<const float4*>(ws + tb + 8 * q);
      float ra[4] = {rv.x, rv.y, rv.z, rv.w};
#pragma unroll
      for (int j = 0; j < 4; ++j) {
        float sc = ra[j] + acc[4 * q + j];   // r2n + dot, maximize
        int kg = tb + 8 * q + j;
        if (sc > best) { best = sc; bidx = kg; }
      }
    }
    if (r < 127) {
      float xs[8] = {p0.x, p0.y, p0.z, p0.w, p1.x, p1.y, p1.z, p1.w};
      bf16x8 hi, lo;
#pragma unroll
      for (int j = 0; j < 8; ++j) {
        __bf16 h = (__bf16)xs[j];
        hi[j] = h; lo[j] = (__bf16)(xs[j] - (float)h);
      }
      unsigned wo = (unsigned)(buf ^ 1) * 32768u + st_off;
      *reinterpret_cast<bf16x8*>(lds + wo)        = hi;
      *reinterpret_cast<bf16x8*>(lds + wo + 8192) = lo;
    }
    __syncthreads();
  }
  {
    float ob = __shfl_xor(best, 32, 64);
    int   oi = __shfl_xor(bidx, 32, 64);
    if (ob > best || (ob == best && oi < bidx)) { best = ob; bidx = oi; }
  }
  float* mf  = reinterpret_cast<float*>(lds);
  int*   mi  = reinterpret_cast<int*>(lds + 1024);
  int*   mix = reinterpret_cast<int*>(lds + 2048);
  if (l < 32) { mf[w * 32 + c] = best; mi[w * 32 + c] = bidx; }
  __syncthreads();
  if (tid < 128) {
    int rgg = tid >> 5, rl = tid & 31;
    float b0 = mf[(2 * rgg) * 32 + rl];     int i0 = mi[(2 * rgg) * 32 + rl];
    float b1 = mf[(2 * rgg + 1) * 32 + rl]; int i1 = mi[(2 * rgg + 1) * 32 + rl];
    int idx = (b1 > b0 || (b1 == b0 && i1 < i0)) ? i1 : i0;
    mix[tid] = idx;
    out[NQ + 2 + rowbase + tid] = (float)idx;
  }
  __syncthreads();
  {
    const int row_l = tid >> 2, seg = tid & 3;
    const int idx  = mix[row_l];
    const int grow = rowbase + row_l;
    const float4* qp = reinterpret_cast<const float4*>(cb + (size_t)idx * D_DIM + seg * 16);
    const float4* zp = reinterpret_cast<const float4*>(z + (size_t)grow * D_DIM + seg * 16);
    float4*       op = reinterpret_cast<float4*>(out + (size_t)grow * D_DIM + seg * 16);
    float lp = 0.f;
#pragma unroll
    for (int cc = 0; cc < 4; ++cc) {
      float4 qv = qp[cc], zv = zp[cc];
      op[cc] = qv;
      float dx = zv.x - qv.x, dy = zv.y - qv.y;
      float dz = zv.z - qv.z, dw = zv.w - qv.w;
      lp += (dx * dx + dy * dy) + (dz * dz + dw * dw);
    }
#pragma unroll
    for (int off = 32; off > 0; off >>= 1) lp += __shfl_down(lp, off, 64);
    if (l == 0) atomicAdd(ws + WS_LOSS, lp);
  }
}

// ------------------------------------------------------------ finalize kernel
__global__ void vq_fin(const float* __restrict__ ws, float* __restrict__ out) {
  float mm = ws[WS_LOSS] * (1.0f / (float)(N_ROWS * D_DIM));
  out[NQ]     = mm;
  out[NQ + 1] = mm;
}

// -------------------------------------------------------------------- launch
extern "C" void kernel_launch(void* const* d_in, const int* in_sizes, int n_in,
                              void* d_out, int out_size, void* d_ws, size_t ws_size,
                              hipStream_t stream) {
  (void)in_sizes; (void)n_in; (void)out_size;
  const float* z  = (const float*)d_in[0];
  const float* cb = (const float*)d_in[1];
  float* out = (float*)d_out;
  float* ws  = (float*)d_ws;

  vq_prep<<<K_CB / 256, 256, 0, stream>>>(cb, ws);
  if (ws_size >= WS_NEED) {
    vq_split<<<256, 256, 0, stream>>>(cb, ws);
    vq_gd2<<<N_ROWS / 128, 512, 0, stream>>>(z, cb, ws, out);
  } else {
    vq_main_reg<<<N_ROWS / 128, 512, 0, stream>>>(z, cb, ws, out);
  }
  vq_fin<<<1, 1, 0, stream>>>(ws, out);
}